// Round 5
// baseline (403.785 us; speedup 1.0000x reference)
//
#include <hip/hip_runtime.h>

// NonMaxSuppression: 3x3 local max + thr>=0.6 + 10px border -> ordered (y,x) coords.
// Input fixed: (16,1,1536,1536) fp32.
// SINGLE-PASS decoupled-lookback kernel (no grid barrier, full occupancy):
//  - ticket = atomicAdd -> tile index in start order (dispatch-order-safe lookback)
//  - NMS phase (R3-proven): 16-row strip, thread = 4 aligned cols, ONE aligned
//    float4/row + 2 wave shuffles for the 6-wide halo, separable v_max3 rolling
//    window. 384 u64 mask chunks -> LDS (1 per thread), never HBM.
//  - block scan of chunk popcounts; publish PARTIAL(agg); wave-0 decoupled
//    lookback over predecessors (agent-scope acquire); publish INCLUSIVE.
//  - scatter (R3-proven): stage packed (y|x<<16) in LDS, coalesced write of both
//    output streams; direct-scatter fallback past CAP keeps any input correct.
// Workspace: [0..8) ticket, [8..8+1536*8) status words — zeroed via hipMemsetAsync.
#define W 1536
#define H 1536
#define NB 16
#define NROWS (NB * H)          // 24576
#define SH 16                   // rows per tile strip
#define NTILE (NROWS / SH)      // 1536
#define BLOCK 384               // 1536/4 cols per thread
#define CPR 24                  // u64 chunks per row
#define CHUNKS (SH * CPR)       // 384 = BLOCK (1 chunk per thread)
#define NW (BLOCK / 64)         // 6 waves
#define CAP 4096                // staged items/tile (16 KB LDS); expected ~2150 (+42 sigma)
#define REP_THR 0.6f
#define FLAG_PARTIAL   (1ull << 62)
#define FLAG_INCLUSIVE (2ull << 62)

__device__ __forceinline__ float max3f(float a, float b, float c) {
    return fmaxf(fmaxf(a, b), c);  // v_max3_f32
}

__global__ __launch_bounds__(BLOCK) void nms_onepass(const float* __restrict__ in,
                                                     unsigned int* __restrict__ ticket,
                                                     unsigned long long* __restrict__ status,
                                                     int* __restrict__ out,
                                                     unsigned int K) {
    __shared__ unsigned long long lmask[CHUNKS];   // 3 KB
    __shared__ unsigned wtot[NW];
    __shared__ unsigned pk[CAP];                   // 16 KB packed y | x<<16
    __shared__ unsigned sTile, sBase;

    const int t = threadIdx.x, lane = t & 63, wv = t >> 6;
    if (t == 0) sTile = atomicAdd(ticket, 1u);     // monotone start order
    __syncthreads();
    const int tile = (int)sTile;
    const int r0 = tile * SH;                      // first output row (global)
    const int ytile = tile % (H / SH);             // strip index within image

    const int c0 = 4 * t;                          // aligned float4 column base
    const int cl = (t == 0) ? 0 : c0 - 1;          // wave-edge halo cols (clamped)
    const int cr = (t == BLOCK - 1) ? (W - 1) : c0 + 4;

    // x-border nibble mask, valid x in [10, 1526); bit j <-> col 4t+j
    unsigned colm = 0xFu;
    if (t <= 1) colm = 0u;
    else if (t == 2) colm = 0xCu;
    if (t >= 382) colm = 0u;
    else if (t == 381) colm = 0x3u;

    auto rowp = [&](int i) {                       // input row rel i (rel 0 = r0-1), clamped
        int ir = r0 - 1 + i;
        ir = ir < 0 ? 0 : (ir >= NROWS ? NROWS - 1 : ir);
        return in + (size_t)ir * W;
    };

    // halo via wave shuffle: h[j] = max of cols c0+j-1 .. c0+j+1
    auto mkhalo = [&](float4 v, float lw, float rx) {
        float lw_all = __shfl_up(v.w, 1, 64);
        if (lane == 0) lw_all = lw;
        float rx_all = __shfl_down(v.x, 1, 64);
        if (lane == 63) rx_all = rx;
        float4 h;
        h.x = max3f(lw_all, v.x, v.y);
        h.y = max3f(v.x, v.y, v.z);
        h.z = max3f(v.y, v.z, v.w);
        h.w = max3f(v.z, v.w, rx_all);
        return h;
    };

    // ---------- NMS phase (masks -> LDS) ----------
    float4 v0 = *(const float4*)(rowp(0) + c0);
    float lw0 = 0.f, rx0 = 0.f;
    if (lane == 0) lw0 = rowp(0)[cl];
    if (lane == 63) rx0 = rowp(0)[cr];
    float4 v1 = *(const float4*)(rowp(1) + c0);
    float lw1 = 0.f, rx1 = 0.f;
    if (lane == 0) lw1 = rowp(1)[cl];
    if (lane == 63) rx1 = rowp(1)[cr];
    float4 vN = *(const float4*)(rowp(2) + c0);
    float lwN = 0.f, rxN = 0.f;
    if (lane == 0) lwN = rowp(2)[cl];
    if (lane == 63) rxN = rowp(2)[cr];

    float4 hA = mkhalo(v0, lw0, rx0);
    float4 hB = mkhalo(v1, lw1, rx1);
    float4 ctrB = v1;

#pragma unroll
    for (int i = 2; i <= SH + 1; ++i) {
        float4 v = vN;
        float lwc = lwN, rxc = rxN;
        vN = *(const float4*)(rowp(i + 1) + c0);   // depth-1 prefetch (clamped)
        lwN = 0.f; rxN = 0.f;
        if (lane == 0) lwN = rowp(i + 1)[cl];
        if (lane == 63) rxN = rowp(i + 1)[cr];

        float4 hC = mkhalo(v, lwc, rxc);

        const int yloc = ytile * SH + (i - 2);
        unsigned nib = 0u;
        if (yloc >= 10 && yloc < H - 10) {
            nib |= (ctrB.x >= fmaxf(max3f(hA.x, hB.x, hC.x), REP_THR)) ? 1u : 0u;
            nib |= (ctrB.y >= fmaxf(max3f(hA.y, hB.y, hC.y), REP_THR)) ? 2u : 0u;
            nib |= (ctrB.z >= fmaxf(max3f(hA.z, hB.z, hC.z), REP_THR)) ? 4u : 0u;
            nib |= (ctrB.w >= fmaxf(max3f(hA.w, hB.w, hC.w), REP_THR)) ? 8u : 0u;
            nib &= colm;
        }
        // fold 16 lanes' nibbles -> u64 chunk (lane%16==0 stores to LDS)
        unsigned x = nib;
        x |= __shfl_down(x, 1, 64) << 4;
        x |= __shfl_down(x, 2, 64) << 8;
        x |= __shfl_down(x, 4, 64) << 16;
        unsigned hi = __shfl_down(x, 8, 64);
        if ((lane & 15) == 0) {
            unsigned long long m64 = (unsigned long long)x | ((unsigned long long)hi << 32);
            lmask[(i - 2) * CPR + (t >> 4)] = m64;
        }
        hA = hB; hB = hC; ctrB = v;
    }
    __syncthreads();

    // ---------- block scan of chunk popcounts ----------
    unsigned long long bits = lmask[t];            // thread t owns chunk t (spatial order)
    const unsigned cnt = (unsigned)__popcll(bits);
    unsigned incl = cnt;
#pragma unroll
    for (int o = 1; o < 64; o <<= 1) {
        unsigned u = __shfl_up(incl, o, 64);
        if (lane >= o) incl += u;
    }
    if (lane == 63) wtot[wv] = incl;
    __syncthreads();

    // ---------- publish + decoupled lookback (wave 0) ----------
    if (wv == 0) {
        unsigned agg = 0;
#pragma unroll
        for (int k = 0; k < NW; ++k) agg += wtot[k];
        if (lane == 0 && tile > 0)
            __hip_atomic_store(&status[tile], FLAG_PARTIAL | (unsigned long long)agg,
                               __ATOMIC_RELEASE, __HIP_MEMORY_SCOPE_AGENT);
        unsigned long long excl = 0;
        int idx = tile - 1;
        while (idx >= 0) {
            const int src = idx - lane;
            unsigned long long s;
            if (src >= 0) {
                do {
                    s = __hip_atomic_load(&status[src], __ATOMIC_ACQUIRE,
                                          __HIP_MEMORY_SCOPE_AGENT);
                } while (!(s >> 62));              // spin until >= PARTIAL
            } else {
                s = FLAG_INCLUSIVE;                // virtual inclusive-0 below tile 0
            }
            const unsigned long long val = s & 0xFFFFFFFFull;
            const unsigned long long ball = __ballot((s >> 62) == 2ull);
            if (ball) {                            // nearest INCLUSIVE at lane li
                const int li = __ffsll((unsigned long long)ball) - 1;
                unsigned long long contrib = (lane <= li) ? val : 0ull;
#pragma unroll
                for (int o = 32; o > 0; o >>= 1) contrib += __shfl_down(contrib, o, 64);
                excl += __shfl(contrib, 0, 64);
                break;
            } else {                               // all 64 PARTIAL: consume window, go back
                unsigned long long contrib = val;
#pragma unroll
                for (int o = 32; o > 0; o >>= 1) contrib += __shfl_down(contrib, o, 64);
                excl += __shfl(contrib, 0, 64);
                idx -= 64;
            }
        }
        if (lane == 0) {
            __hip_atomic_store(&status[tile],
                               FLAG_INCLUSIVE | (excl + (unsigned long long)agg),
                               __ATOMIC_RELEASE, __HIP_MEMORY_SCOPE_AGENT);
            sBase = (unsigned)excl;
        }
    }
    __syncthreads();

    // ---------- staged coalesced scatter ----------
    const unsigned blockBase = sBase;
    unsigned blockCnt = 0, wbase = 0;
#pragma unroll
    for (int k = 0; k < NW; ++k) {
        blockCnt += wtot[k];
        if (k < wv) wbase += wtot[k];
    }
    unsigned local = wbase + (incl - cnt);         // block-local index of first item
    if (bits) {
        const int y = ytile * SH + t / CPR;
        const int x0 = (t % CPR) * 64;
        while (bits) {
            int j = __builtin_ctzll(bits);
            bits &= bits - 1ull;
            if (local < CAP) {
                pk[local] = (unsigned)y | ((unsigned)(x0 + j) << 16);
            } else {                               // overflow fallback (any input correct)
                unsigned g = blockBase + local;
                if (g < K) { out[g] = y; out[K + g] = x0 + j; }
            }
            ++local;
        }
    }
    __syncthreads();
    const unsigned lim = blockCnt < CAP ? blockCnt : CAP;
    for (unsigned i = t; i < lim; i += BLOCK) {
        unsigned g = blockBase + i;
        if (g < K) {
            unsigned p = pk[i];
            out[g] = (int)(p & 0xFFFFu);
            out[K + g] = (int)(p >> 16);
        }
    }
}

extern "C" void kernel_launch(void* const* d_in, const int* in_sizes, int n_in,
                              void* d_out, int out_size, void* d_ws, size_t ws_size,
                              hipStream_t stream) {
    const float* in = (const float*)d_in[0];
    int* out = (int*)d_out;
    unsigned int* ticket = (unsigned int*)d_ws;
    unsigned long long* status = (unsigned long long*)((char*)d_ws + 8);
    const unsigned K = (unsigned)(out_size / 2);

    hipMemsetAsync(d_ws, 0, 8 + (size_t)NTILE * 8, stream);  // ticket + status flags
    nms_onepass<<<NTILE, BLOCK, 0, stream>>>(in, ticket, status, out, K);
}

// Round 6
// 231.308 us; speedup vs baseline: 1.7457x; 1.7457x over previous
//
#include <hip/hip_runtime.h>

// NonMaxSuppression: 3x3 local max + thr>=0.6 + 10px border -> ordered (y,x) coords.
// Input fixed: (16,1,1536,1536) fp32.
// Pass1: barrier-free rolling-register NMS. 1536 blocks x 192 threads; block = 16 rows,
//        thread = 8 aligned cols (TWO aligned float4/row). One wave-shuffle pair + 2
//        predicated edge scalars give the 10-wide halo; separable v_max3 vertical
//        window rolls in registers. VALU/byte ~1.65x lower than the 4-col version.
//        u64 masks + per-block counts to global.
// Pass2 (fused scan+scatter, R3-proven): 768 blocks x 768 threads (32-row strips).
//        Block offset from the 1536 counts (2 loads/thread + reduce). Replay masks
//        into LDS as packed (y|x<<16), then COALESCED write of both output streams.
//        Direct-scatter fallback past CAP keeps arbitrary inputs correct.
#define W 1536
#define H 1536
#define NB 16
#define NROWS (NB * H)          // 24576
#define SH1 16                  // rows per pass1 block
#define NBLK1 (NROWS / SH1)     // 1536
#define BLOCK1 192              // 1536/8 cols per thread
#define NW1 (BLOCK1 / 64)       // 3 waves
#define CPR 24                  // u64 chunks per row
#define NMASK (NROWS * CPR)     // 589824 u64 = 4.72 MB
#define SH2 32                  // rows per scatter block
#define NBLK2 (NROWS / SH2)     // 768
#define BLOCK2 (SH2 * CPR)      // 768 threads
#define CAP 6144                // staged items/block (24 KB LDS); expected ~4300 peak-load
#define REP_THR 0.6f

__device__ __forceinline__ float max3f(float a, float b, float c) {
    return fmaxf(fmaxf(a, b), c);  // v_max3_f32
}

struct f8 { float4 a, b; };

__global__ __launch_bounds__(BLOCK1) void nms_pass1(const float* __restrict__ in,
                                                    unsigned long long* __restrict__ masks,
                                                    unsigned int* __restrict__ counts) {
    const int t = threadIdx.x;
    const int lane = t & 63;
    const int wv = t >> 6;
    const int blk = blockIdx.x;
    const int r0 = blk * SH1;                // first output row (global)
    const int ytile = blk % (H / SH1);       // strip index within image

    const int c0 = 8 * t;                    // aligned column base (32B-aligned)
    // wave-edge halo columns (clamped; clamped lanes masked by colm)
    const int cl = (t == 0) ? 0 : c0 - 1;
    const int cr = (t == BLOCK1 - 1) ? (W - 1) : c0 + 8;

    // x-border byte mask, valid x in [10, 1526); bit j <-> col 8t+j
    unsigned colm = 0xFFu;
    if (t == 0) colm = 0u;
    else if (t == 1) colm = 0xFCu;           // cols 8,9 invalid
    if (t == BLOCK1 - 1) colm = 0u;
    else if (t == BLOCK1 - 2) colm = 0x3Fu;  // cols 1526,1527 invalid

    auto rowp = [&](int i) {                 // input row rel i (rel 0 = r0-1), clamped
        int ir = r0 - 1 + i;
        ir = ir < 0 ? 0 : (ir >= NROWS ? NROWS - 1 : ir);
        return in + (size_t)ir * W;
    };

    // 8-wide horizontal max-halo: h[j] = max of cols c0+j-1 .. c0+j+1
    auto mkhalo = [&](float4 va, float4 vb, float l, float r) {
        float lw = __shfl_up(vb.w, 1, 64);
        if (lane == 0) lw = l;               // from predicated edge load
        float rx = __shfl_down(va.x, 1, 64);
        if (lane == 63) rx = r;
        f8 h;
        h.a.x = max3f(lw,   va.x, va.y);
        h.a.y = max3f(va.x, va.y, va.z);
        h.a.z = max3f(va.y, va.z, va.w);
        h.a.w = max3f(va.z, va.w, vb.x);
        h.b.x = max3f(va.w, vb.x, vb.y);
        h.b.y = max3f(vb.x, vb.y, vb.z);
        h.b.z = max3f(vb.y, vb.z, vb.w);
        h.b.w = max3f(vb.z, vb.w, rx);
        return h;
    };

    // prologue: rows rel 0,1 and prefetch rel 2
    float4 va0 = *(const float4*)(rowp(0) + c0);
    float4 vb0 = *(const float4*)(rowp(0) + c0 + 4);
    float lw0 = 0.f, rx0 = 0.f;
    if (lane == 0) lw0 = rowp(0)[cl];
    if (lane == 63) rx0 = rowp(0)[cr];
    float4 va1 = *(const float4*)(rowp(1) + c0);
    float4 vb1 = *(const float4*)(rowp(1) + c0 + 4);
    float lw1 = 0.f, rx1 = 0.f;
    if (lane == 0) lw1 = rowp(1)[cl];
    if (lane == 63) rx1 = rowp(1)[cr];
    float4 vaN = *(const float4*)(rowp(2) + c0);
    float4 vbN = *(const float4*)(rowp(2) + c0 + 4);
    float lwN = 0.f, rxN = 0.f;
    if (lane == 0) lwN = rowp(2)[cl];
    if (lane == 63) rxN = rowp(2)[cr];

    f8 hA = mkhalo(va0, vb0, lw0, rx0);
    f8 hB = mkhalo(va1, vb1, lw1, rx1);
    f8 ctr;                                  // center row values (cols c0..c0+7)
    ctr.a = va1; ctr.b = vb1;

    unsigned cnt = 0;
#pragma unroll
    for (int i = 2; i <= SH1 + 1; ++i) {
        float4 va = vaN, vb = vbN;
        float lwc = lwN, rxc = rxN;
        vaN = *(const float4*)(rowp(i + 1) + c0);       // depth-1 prefetch (clamped)
        vbN = *(const float4*)(rowp(i + 1) + c0 + 4);
        lwN = 0.f; rxN = 0.f;
        if (lane == 0) lwN = rowp(i + 1)[cl];
        if (lane == 63) rxN = rowp(i + 1)[cr];

        f8 hC = mkhalo(va, vb, lwc, rxc);

        const int yloc = ytile * SH1 + (i - 2);         // image-local y of emitted row
        unsigned nib = 0u;
        if (yloc >= 10 && yloc < H - 10) {
            nib |= (ctr.a.x >= fmaxf(max3f(hA.a.x, hB.a.x, hC.a.x), REP_THR)) ?   1u : 0u;
            nib |= (ctr.a.y >= fmaxf(max3f(hA.a.y, hB.a.y, hC.a.y), REP_THR)) ?   2u : 0u;
            nib |= (ctr.a.z >= fmaxf(max3f(hA.a.z, hB.a.z, hC.a.z), REP_THR)) ?   4u : 0u;
            nib |= (ctr.a.w >= fmaxf(max3f(hA.a.w, hB.a.w, hC.a.w), REP_THR)) ?   8u : 0u;
            nib |= (ctr.b.x >= fmaxf(max3f(hA.b.x, hB.b.x, hC.b.x), REP_THR)) ?  16u : 0u;
            nib |= (ctr.b.y >= fmaxf(max3f(hA.b.y, hB.b.y, hC.b.y), REP_THR)) ?  32u : 0u;
            nib |= (ctr.b.z >= fmaxf(max3f(hA.b.z, hB.b.z, hC.b.z), REP_THR)) ?  64u : 0u;
            nib |= (ctr.b.w >= fmaxf(max3f(hA.b.w, hB.b.w, hC.b.w), REP_THR)) ? 128u : 0u;
            nib &= colm;
        }
        cnt += __popc(nib);
        // fold 8 lanes' bytes -> u64 chunk (lane%8==0 stores); byte k of chunk = lane 8c+k
        unsigned x = nib;
        x |= __shfl_down(x, 1, 64) << 8;
        x |= __shfl_down(x, 2, 64) << 16;
        unsigned hi = __shfl_down(x, 4, 64);
        if ((lane & 7) == 0) {
            unsigned long long m64 = (unsigned long long)x | ((unsigned long long)hi << 32);
            masks[(size_t)(r0 + i - 2) * CPR + (t >> 3)] = m64;
        }
        hA = hB; hB = hC; ctr.a = va; ctr.b = vb;
    }

#pragma unroll
    for (int o = 32; o > 0; o >>= 1) cnt += __shfl_down(cnt, o, 64);
    __shared__ unsigned wsum[NW1];
    if (lane == 0) wsum[wv] = cnt;
    __syncthreads();
    if (t == 0) {
        unsigned s = 0;
#pragma unroll
        for (int k = 0; k < NW1; ++k) s += wsum[k];
        counts[blk] = s;
    }
}

// Pass 2: fused scan + scatter with LDS-staged coalesced output (R3-proven, unchanged).
// One u64 chunk per thread (row-major => thread order == spatial order).
__global__ __launch_bounds__(BLOCK2) void nms_scatter(const unsigned long long* __restrict__ masks,
                                                      const unsigned int* __restrict__ counts,
                                                      int* __restrict__ out, unsigned int K) {
    __shared__ unsigned wtot[BLOCK2 / 64];
    __shared__ unsigned sred[BLOCK2 / 64];
    __shared__ unsigned pk[CAP];             // packed y | x<<16
    const int t = threadIdx.x, lane = t & 63, wv = t >> 6;
    const int blk = blockIdx.x;
    unsigned long long bits = masks[(size_t)blk * BLOCK2 + t];
    const unsigned cnt = (unsigned)__popcll(bits);
    unsigned incl = cnt;
#pragma unroll
    for (int o = 1; o < 64; o <<= 1) {
        unsigned u = __shfl_up(incl, o, 64);
        if (lane >= o) incl += u;
    }
    // exclusive block offset: sum of counts[0..2*blk) over 1536 pass1 counts
    unsigned part = 0;
    if (t < 2 * blk) part += counts[t];
    if (t + BLOCK2 < 2 * blk) part += counts[t + BLOCK2];
#pragma unroll
    for (int o = 32; o > 0; o >>= 1) part += __shfl_down(part, o, 64);
    if (lane == 63) wtot[wv] = incl;
    if (lane == 0) sred[wv] = part;
    __syncthreads();
    unsigned blockBase = 0, blockCnt = 0, wbase = 0;
#pragma unroll
    for (int k = 0; k < BLOCK2 / 64; ++k) {
        blockBase += sred[k];
        blockCnt += wtot[k];
        if (k < wv) wbase += wtot[k];
    }
    unsigned local = wbase + (incl - cnt);   // block-local index of this thread's first item
    if (bits) {
        const int y = (blk % (H / SH2)) * SH2 + t / CPR;   // image-local row
        const int x0 = (t % CPR) * 64;
        while (bits) {
            int j = __builtin_ctzll(bits);
            bits &= bits - 1ull;
            if (local < CAP) {
                pk[local] = (unsigned)y | ((unsigned)(x0 + j) << 16);
            } else {                          // overflow fallback (correct for any input)
                unsigned g = blockBase + local;
                if (g < K) { out[g] = y; out[K + g] = x0 + j; }
            }
            ++local;
        }
    }
    __syncthreads();
    const unsigned lim = blockCnt < CAP ? blockCnt : CAP;
    for (unsigned i = t; i < lim; i += BLOCK2) {
        unsigned g = blockBase + i;
        if (g < K) {
            unsigned p = pk[i];
            out[g] = (int)(p & 0xFFFFu);
            out[K + g] = (int)(p >> 16);
        }
    }
}

extern "C" void kernel_launch(void* const* d_in, const int* in_sizes, int n_in,
                              void* d_out, int out_size, void* d_ws, size_t ws_size,
                              hipStream_t stream) {
    const float* in = (const float*)d_in[0];
    int* out = (int*)d_out;
    unsigned long long* masks = (unsigned long long*)d_ws;
    unsigned int* counts = (unsigned int*)((char*)d_ws + (size_t)NMASK * 8);
    const unsigned K = (unsigned)(out_size / 2);

    nms_pass1<<<NBLK1, BLOCK1, 0, stream>>>(in, masks, counts);
    nms_scatter<<<NBLK2, BLOCK2, 0, stream>>>(masks, counts, out, K);
}